// Round 7
// baseline (22.160 us; speedup 1.0000x reference)
//
#include <hip/hip_runtime.h>
#include <math.h>

#define LAMBDA_OPACITY 0.001f
#define LAMBDA_DISTORTION 0.001f

// Fused NeRF loss, single dispatch, uniform grid (2048 blocks = 8/CU).
// Distortion: loss = 2*sum_{j<i} w_i w_j (t_i - t_j) + sum w^2 d / 3.
// 16 lanes/ray ("group"), 8 samples/lane, 4 rays/wave (= one "quad").
// Each wave processes TWO quads, software-pipelined: both headers + both
// quads' 12 dwordx4 loads issued before any compute (12 KB in flight/wave).
// Elemwise rgb/opacity handled by the first 256 blocks (contiguous float4).
// No nontemporal hints: inputs are Infinity-Cache-resident across replays (R5).

__global__ void __launch_bounds__(256) fused_nerf_loss(
        const float* __restrict__ rgb,
        const float* __restrict__ target_rgb,
        const float* __restrict__ opacity,
        const float* __restrict__ ws,
        const float* __restrict__ deltas,
        const float* __restrict__ ts,
        const int* __restrict__ rays_a,
        float* __restrict__ out_rgb,
        float* __restrict__ out_op,
        float* __restrict__ out_dist,
        int n_rgb, int n_rays, int n_quads, int total_waves, int ew_chunks) {
    const int tid  = threadIdx.x;
    const int wave = tid >> 6;
    const int lane = tid & 63;
    const int sub  = lane & 15;
    const int grp  = lane >> 4;
    const int wgid = blockIdx.x * 4 + wave;

    // ---------- stage 1: headers + prefetch for both quads ----------
    const int q0 = wgid;
    const int q1 = wgid + total_waves;

    int oi0 = 0, st0 = 0, ct0 = 0;
    const int ray0 = q0 * 4 + grp;
    const bool v0 = (q0 < n_quads) && (ray0 < n_rays);
    if (v0) { oi0 = rays_a[ray0*3]; st0 = rays_a[ray0*3+1]; ct0 = rays_a[ray0*3+2]; }

    int oi1 = 0, st1 = 0, ct1 = 0;
    const int ray1 = q1 * 4 + grp;
    const bool v1 = (q1 < n_quads) && (ray1 < n_rays);
    if (v1) { oi1 = rays_a[ray1*3]; st1 = rays_a[ray1*3+1]; ct1 = rays_a[ray1*3+2]; }

    const int i0a = sub * 8;
    const bool pf0 = v0 && (i0a + 8 <= ct0);
    const bool pf1 = v1 && (i0a + 8 <= ct1);

    float4 Aw0, Aw1, At0, At1, Ad0, Ad1;
    float4 Bw0, Bw1, Bt0, Bt1, Bd0, Bd1;
    if (pf0) {
        Aw0 = *reinterpret_cast<const float4*>(ws     + st0 + i0a);
        Aw1 = *reinterpret_cast<const float4*>(ws     + st0 + i0a + 4);
        At0 = *reinterpret_cast<const float4*>(ts     + st0 + i0a);
        At1 = *reinterpret_cast<const float4*>(ts     + st0 + i0a + 4);
        Ad0 = *reinterpret_cast<const float4*>(deltas + st0 + i0a);
        Ad1 = *reinterpret_cast<const float4*>(deltas + st0 + i0a + 4);
    }
    if (pf1) {
        Bw0 = *reinterpret_cast<const float4*>(ws     + st1 + i0a);
        Bw1 = *reinterpret_cast<const float4*>(ws     + st1 + i0a + 4);
        Bt0 = *reinterpret_cast<const float4*>(ts     + st1 + i0a);
        Bt1 = *reinterpret_cast<const float4*>(ts     + st1 + i0a + 4);
        Bd0 = *reinterpret_cast<const float4*>(deltas + st1 + i0a);
        Bd1 = *reinterpret_cast<const float4*>(deltas + st1 + i0a + 4);
    }

    // ---------- elementwise (first ew_blocks blocks, whole-block) ----------
    {
        const int chunk = blockIdx.x * 256 + tid;
        if (chunk < ew_chunks) {
            const int e = chunk * 4;
            if (e < n_rgb) {
                float4 a = *reinterpret_cast<const float4*>(rgb + e);
                float4 b = *reinterpret_cast<const float4*>(target_rgb + e);
                float4 r;
                r.x = (a.x-b.x)*(a.x-b.x); r.y = (a.y-b.y)*(a.y-b.y);
                r.z = (a.z-b.z)*(a.z-b.z); r.w = (a.w-b.w)*(a.w-b.w);
                *reinterpret_cast<float4*>(out_rgb + e) = r;
            } else if (e < n_rgb + n_rays) {
                const int oi = e - n_rgb;
                float4 o = *reinterpret_cast<const float4*>(opacity + oi);
                float ox = o.x+1e-10f, oy = o.y+1e-10f, oz = o.z+1e-10f, ow = o.w+1e-10f;
                float4 r;
                r.x = LAMBDA_OPACITY * (-ox * logf(ox));
                r.y = LAMBDA_OPACITY * (-oy * logf(oy));
                r.z = LAMBDA_OPACITY * (-oz * logf(oz));
                r.w = LAMBDA_OPACITY * (-ow * logf(ow));
                *reinterpret_cast<float4*>(out_op + oi) = r;
            }
        }
    }

    // ---------- stage 2: compute both quads ----------
    #define COMPUTE_QUAD(VAL, OI, ST, CT, PF, W0, W1, T0, T1, D0, D1)          \
    {                                                                          \
        float acc = 0.f, carry_w = 0.f, carry_wt = 0.f;                        \
        for (int base = 0; base < CT; base += 128) {                           \
            const int i0 = base + sub * 8;                                     \
            float w[8], t[8], dl[8];                                           \
            if (base == 0 && PF) {                                             \
                w[0]=W0.x; w[1]=W0.y; w[2]=W0.z; w[3]=W0.w;                    \
                w[4]=W1.x; w[5]=W1.y; w[6]=W1.z; w[7]=W1.w;                    \
                t[0]=T0.x; t[1]=T0.y; t[2]=T0.z; t[3]=T0.w;                    \
                t[4]=T1.x; t[5]=T1.y; t[6]=T1.z; t[7]=T1.w;                    \
                dl[0]=D0.x; dl[1]=D0.y; dl[2]=D0.z; dl[3]=D0.w;                \
                dl[4]=D1.x; dl[5]=D1.y; dl[6]=D1.z; dl[7]=D1.w;                \
            } else {                                                           \
                _Pragma("unroll")                                              \
                for (int k = 0; k < 8; ++k) {                                  \
                    const int i = i0 + k;                                      \
                    const bool vv = (i < CT);                                  \
                    w[k]  = vv ? ws[ST + i]     : 0.f;                         \
                    t[k]  = vv ? ts[ST + i]     : 0.f;                         \
                    dl[k] = vv ? deltas[ST + i] : 0.f;                         \
                }                                                              \
            }                                                                  \
            float lw = 0.f, lwt = 0.f, cpair = 0.f, csq = 0.f;                 \
            _Pragma("unroll")                                                  \
            for (int k = 0; k < 8; ++k) {                                      \
                const float wk = w[k], tk = t[k];                              \
                cpair += wk * (tk * lw - lwt);                                 \
                csq   += wk * wk * dl[k];                                      \
                lw  += wk;                                                     \
                lwt += wk * tk;                                                \
            }                                                                  \
            float sw = lw, swt = lwt;                                          \
            _Pragma("unroll")                                                  \
            for (int off = 1; off < 16; off <<= 1) {                           \
                const float pw  = __shfl_up(sw,  off, 16);                     \
                const float pwt = __shfl_up(swt, off, 16);                     \
                if (sub >= off) { sw += pw; swt += pwt; }                      \
            }                                                                  \
            const float Pw  = sw  - lw  + carry_w;                             \
            const float Pwt = swt - lwt + carry_wt;                            \
            acc += 2.f * (cpair + lwt * Pw - lw * Pwt) + csq * (1.f / 3.f);    \
            if (base + 128 < CT) {                                             \
                carry_w  += __shfl(sw,  15, 16);                               \
                carry_wt += __shfl(swt, 15, 16);                               \
            }                                                                  \
        }                                                                      \
        _Pragma("unroll")                                                      \
        for (int off = 1; off < 16; off <<= 1)                                 \
            acc += __shfl_xor(acc, off, 16);                                   \
        if (VAL && sub == 0)                                                   \
            out_dist[OI] = LAMBDA_DISTORTION * acc;                            \
    }

    COMPUTE_QUAD(v0, oi0, st0, ct0, pf0, Aw0, Aw1, At0, At1, Ad0, Ad1)
    COMPUTE_QUAD(v1, oi1, st1, ct1, pf1, Bw0, Bw1, Bt0, Bt1, Bd0, Bd1)

    // ---------- rare tail: more than 2 quads per wave ----------
    for (int q = wgid + 2 * total_waves; q < n_quads; q += total_waves) {
        const int ray = q * 4 + grp;
        const bool v = (ray < n_rays);
        int oi = 0, st = 0, ct = 0;
        if (v) { oi = rays_a[ray*3]; st = rays_a[ray*3+1]; ct = rays_a[ray*3+2]; }
        const bool pf = false;
        float4 Z0, Z1;
        COMPUTE_QUAD(v, oi, st, ct, pf, Z0, Z1, Z0, Z1, Z0, Z1)
    }
    #undef COMPUTE_QUAD
}

extern "C" void kernel_launch(void* const* d_in, const int* in_sizes, int n_in,
                              void* d_out, int out_size, void* d_ws, size_t ws_size,
                              hipStream_t stream) {
    const float* rgb        = (const float*)d_in[0];
    const float* target_rgb = (const float*)d_in[1];
    const float* opacity    = (const float*)d_in[2];
    const float* ws         = (const float*)d_in[3];
    const float* deltas     = (const float*)d_in[4];
    const float* ts         = (const float*)d_in[5];
    const int*   rays_a     = (const int*)d_in[6];

    const int n_rgb  = in_sizes[0];   // N_RAYS * 3
    const int n_rays = in_sizes[2];   // N_RAYS

    float* out      = (float*)d_out;
    float* out_rgb  = out;
    float* out_op   = out + n_rgb;
    float* out_dist = out + n_rgb + n_rays;

    const int n_quads   = (n_rays + 3) / 4;            // 4 rays per wave-task
    const int ray_blocks = (n_quads + 7) / 8;          // 4 waves x 2 quads per block
    const int ew_chunks = (n_rgb + n_rays + 3) / 4;    // float4 chunks
    const int ew_blocks = (ew_chunks + 255) / 256;
    const int blocks = ray_blocks > ew_blocks ? ray_blocks : ew_blocks;
    const int total_waves = blocks * 4;

    fused_nerf_loss<<<blocks, 256, 0, stream>>>(
        rgb, target_rgb, opacity, ws, deltas, ts, rays_a,
        out_rgb, out_op, out_dist,
        n_rgb, n_rays, n_quads, total_waves, ew_chunks);
}